// Round 3
// baseline (281.512 us; speedup 1.0000x reference)
//
#include <hip/hip_runtime.h>
#include <math.h>

// Time2Vec: out[b,l,d,e] = (e==0) ? x*W[d,0]+b[d,0] : sin(x*W[d,e]+b[d,e])
// B=16, L=8192, D=8, E=64. Output fp32, 67,108,864 elements (256 MiB).
// Memory-bound: ~272 MB HBM traffic -> ~43 us floor at 6.3 TB/s.
//
// One thread per output float4; 16 threads per (b,l,d) row of 64 outputs.
// Consecutive lanes store consecutive 16B segments (perfectly coalesced,
// 1 KiB per wave store). W/b (2 KB each) stay resident in L1.

__device__ __forceinline__ float fast_sin(float a) { return __sinf(a); }

__global__ __launch_bounds__(256) void t2v_kernel(
    const float* __restrict__ x,
    const float* __restrict__ W,   // (8, 64)
    const float* __restrict__ b,   // (8, 64)
    float* __restrict__ out,
    int n_f4)                      // total float4s in output
{
    const int gid = blockIdx.x * blockDim.x + threadIdx.x;
    if (gid >= n_f4) return;

    const int row  = gid >> 4;     // (b,l,d) row index
    const int quad = gid & 15;     // float4 index within E=64

    float xv = x[row];
    xv = (xv != xv) ? 0.0f : xv;   // nan_to_num (inputs finite; NaN guard only)

    const int d = row & 7;         // D == 8
    const float4 w4 = reinterpret_cast<const float4*>(W)[d * 16 + quad];
    const float4 b4 = reinterpret_cast<const float4*>(b)[d * 16 + quad];

    float4 y;
    y.x = fmaf(xv, w4.x, b4.x);
    y.y = fmaf(xv, w4.y, b4.y);
    y.z = fmaf(xv, w4.z, b4.z);
    y.w = fmaf(xv, w4.w, b4.w);

    y.x = (quad == 0) ? y.x : fast_sin(y.x);  // global e==0 passes through
    y.y = fast_sin(y.y);
    y.z = fast_sin(y.z);
    y.w = fast_sin(y.w);

    reinterpret_cast<float4*>(out)[gid] = y;
}

extern "C" void kernel_launch(void* const* d_in, const int* in_sizes, int n_in,
                              void* d_out, int out_size, void* d_ws, size_t ws_size,
                              hipStream_t stream) {
    const float* x = (const float*)d_in[0];
    const float* W = (const float*)d_in[1];
    const float* b = (const float*)d_in[2];
    float* out = (float*)d_out;

    const int n_f4  = out_size / 4;          // 16,777,216 float4 stores
    const int block = 256;
    const int grid  = (n_f4 + block - 1) / block;

    t2v_kernel<<<grid, block, 0, stream>>>(x, W, b, out, n_f4);
}

// Round 4
// 271.527 us; speedup vs baseline: 1.0368x; 1.0368x over previous
//
#include <hip/hip_runtime.h>
#include <math.h>

// Time2Vec: out[b,l,d,e] = (e==0) ? x*W[d,0]+b[d,0] : sin(x*W[d,e]+b[d,e])
// B=16, L=8192, D=8, E=64. Output fp32, 67,108,864 elements (256 MiB).
// Memory-bound: ~272 MB HBM traffic -> ~43 us floor at 6.3 TB/s.
//
// Grid-stride layout trick: stride (grid*block) is a multiple of 128 threads,
// so each thread's (d, quad) coordinates are FIXED across iterations:
//   gid = row*16 + quad, row = bl*8 + d, stride/16 % 8 == 0  =>  d, quad const.
// Therefore W[d][quad*4..] and b[d][quad*4..] are loaded ONCE per thread and
// held in registers for all iterations — removes the per-iteration 64-segment
// L1 gather that competed with the store path. Stores remain perfectly
// coalesced: each wave store instruction covers 1 KiB contiguous.

__global__ __launch_bounds__(256) void t2v_kernel(
    const float* __restrict__ x,
    const float* __restrict__ W,   // (8, 64)
    const float* __restrict__ b,   // (8, 64)
    float* __restrict__ out,
    int n_f4)                      // total float4s in output
{
    const int tid    = blockIdx.x * blockDim.x + threadIdx.x;
    const int stride = gridDim.x * blockDim.x;   // multiple of 128 by launch config
    const int quad   = tid & 15;                 // float4 index within E=64 (fixed)
    const int d      = (tid >> 4) & 7;           // D index (fixed: stride/16 % 8 == 0)

    const float4 w4 = reinterpret_cast<const float4*>(W)[d * 16 + quad];
    const float4 b4 = reinterpret_cast<const float4*>(b)[d * 16 + quad];
    const bool keep0 = (quad == 0);              // global e==0 passes through

    for (int gid = tid; gid < n_f4; gid += stride) {
        const int row = gid >> 4;                // (b,l,d) row index
        float xv = x[row];
        xv = (xv != xv) ? 0.0f : xv;             // nan_to_num

        float4 y;
        y.x = fmaf(xv, w4.x, b4.x);
        y.y = fmaf(xv, w4.y, b4.y);
        y.z = fmaf(xv, w4.z, b4.z);
        y.w = fmaf(xv, w4.w, b4.w);

        y.x = keep0 ? y.x : __sinf(y.x);
        y.y = __sinf(y.y);
        y.z = __sinf(y.z);
        y.w = __sinf(y.w);

        reinterpret_cast<float4*>(out)[gid] = y;
    }
}

extern "C" void kernel_launch(void* const* d_in, const int* in_sizes, int n_in,
                              void* d_out, int out_size, void* d_ws, size_t ws_size,
                              hipStream_t stream) {
    const float* x = (const float*)d_in[0];
    const float* W = (const float*)d_in[1];
    const float* b = (const float*)d_in[2];
    float* out = (float*)d_out;

    const int n_f4  = out_size / 4;   // 16,777,216 float4 stores
    const int block = 256;
    const int grid  = 8192;           // stride = 2,097,152 threads (mult of 128);
                                      // exactly 8 iterations; 32 blocks/CU

    t2v_kernel<<<grid, block, 0, stream>>>(x, W, b, out, n_f4);
}